// Round 4
// baseline (281.944 us; speedup 1.0000x reference)
//
#include <hip/hip_runtime.h>
#include <cstdint>
#include <cstddef>

typedef __attribute__((ext_vector_type(8))) short bf16x8;
typedef __attribute__((ext_vector_type(4))) unsigned short u16x4;
typedef __attribute__((ext_vector_type(4))) float f32x4;
typedef unsigned short u16;

#define T_TOT 9728
#define DDIM  2048
#define GHN   256
#define NSEQ  8

__device__ __constant__ int OFFS[NSEQ + 1] = {0, 512, 1536, 3072, 5120, 5760, 6656, 7936, 9728};

__device__ __forceinline__ u16 f2bf(float f) {
  union { float f; unsigned u; } v; v.f = f;
  unsigned r = v.u + 0x7FFFu + ((v.u >> 16) & 1u);
  return (u16)(r >> 16);
}
__device__ __forceinline__ float silu_f(float v) {
  return v / (1.0f + __expf(-v));
}

// ---------------------------------------------------------------------------
// Prep: fp32 [R][C] -> bf16 [C][R]  (transpose + convert), 64x64 tiles
// (validated round 1)
// ---------------------------------------------------------------------------
__global__ __launch_bounds__(256)
void transpose_bf16_k(const float* __restrict__ in, u16* __restrict__ out, int R, int C) {
  __shared__ float tile[64][65];
  const int c0 = blockIdx.x * 64, r0 = blockIdx.y * 64;
  const int tid = threadIdx.x;
  const int lc = tid & 63, lr = tid >> 6;
#pragma unroll
  for (int p = 0; p < 16; ++p) {
    int r = lr + p * 4;
    tile[r][lc] = in[(size_t)(r0 + r) * C + c0 + lc];
  }
  __syncthreads();
#pragma unroll
  for (int p = 0; p < 16; ++p) {
    int c = lr + p * 4;
    out[(size_t)(c0 + c) * R + r0 + lc] = f2bf(tile[lc][c]);
  }
}

// ---------------------------------------------------------------------------
// Kernel A: h = silu(gi @ w1), bf16 MFMA.  BM=32, N=256 (full), BK=64.
// (validated round-1 kernel; ONLY the final store line changed: h is stored
//  PRE-SWIZZLED: element (t,c) at t*256 + ((c>>3)^(t&7))*8 + (c&7).)
// grid = T/32 = 304 blocks, 256 threads (4 waves; wave w owns cols [w*64,w*64+64)).
// ---------------------------------------------------------------------------
__global__ __launch_bounds__(256, 4)
void gemm1_silu(const float* __restrict__ gi, const u16* __restrict__ w1T,
                u16* __restrict__ h) {
  __shared__ u16 A[32][72];  // +8 pad keeps ds_read_b128 16B-aligned
  const int tid = threadIdx.x;
  const int lane = tid & 63, wid = tid >> 6;
  const int l15 = lane & 15, l4 = lane >> 4;
  const int t0 = blockIdx.x * 32;
  const int nb = wid * 64;

  f32x4 acc[2][4] = {};

  for (int k0 = 0; k0 < DDIM; k0 += 64) {
    // stage gi chunk [32][64] fp32 -> bf16 LDS (coalesced float4 reads)
#pragma unroll
    for (int j = 0; j < 2; ++j) {
      int idx = tid + j * 256;            // 0..511
      int m = idx >> 4, f4 = idx & 15;    // 32 rows x 16 float4
      f32x4 v = *reinterpret_cast<const f32x4*>(&gi[(size_t)(t0 + m) * DDIM + k0 + f4 * 4]);
      u16x4 b;
      b[0] = f2bf(v[0]); b[1] = f2bf(v[1]); b[2] = f2bf(v[2]); b[3] = f2bf(v[3]);
      *reinterpret_cast<u16x4*>(&A[m][f4 * 4]) = b;
    }
    __syncthreads();
#pragma unroll
    for (int ks = 0; ks < 2; ++ks) {
      bf16x8 af[2], bfr[4];
#pragma unroll
      for (int mi = 0; mi < 2; ++mi)
        af[mi] = *reinterpret_cast<const bf16x8*>(&A[mi * 16 + l15][ks * 32 + 8 * l4]);
#pragma unroll
      for (int ni = 0; ni < 4; ++ni)
        bfr[ni] = *reinterpret_cast<const bf16x8*>(
            &w1T[(size_t)(nb + ni * 16 + l15) * DDIM + k0 + ks * 32 + 8 * l4]);
#pragma unroll
      for (int mi = 0; mi < 2; ++mi)
#pragma unroll
        for (int ni = 0; ni < 4; ++ni)
          acc[mi][ni] = __builtin_amdgcn_mfma_f32_16x16x32_bf16(af[mi], bfr[ni], acc[mi][ni], 0, 0, 0);
    }
    __syncthreads();
  }

  // epilogue: silu, store h in SWIZZLED layout (bijective column permutation)
#pragma unroll
  for (int mi = 0; mi < 2; ++mi)
#pragma unroll
    for (int ni = 0; ni < 4; ++ni)
#pragma unroll
      for (int r = 0; r < 4; ++r) {
        float v = silu_f(acc[mi][ni][r]);
        int token = t0 + mi * 16 + l4 * 4 + r;   // C/D: row=(l>>4)*4+r
        int c = nb + ni * 16 + l15;              //       col=l&15
        int pos = ((((c >> 3) ^ (token & 7)) << 3) | (c & 7));
        h[(size_t)token * GHN + pos] = f2bf(v);
      }
}

// ---------------------------------------------------------------------------
// Kernel B: fused kern = h@w2+b2 -> 4-tap conv -> silu -> out.
// grid (38 token-groups, 32 d-tiles); 256 thr / 4 waves.
// w2 frags register-resident (128 VGPR), loaded once; 4 token-tiles of 64 per
// block; single-buffer LDS staging with plain vector loads (h pre-swizzled so
// the copy is linear); wave-private conv exchange (compiler-fenced).
// ---------------------------------------------------------------------------
__global__ __launch_bounds__(256, 2)
void gemm2_conv(const u16* __restrict__ h, const u16* __restrict__ w2T,
                const float* __restrict__ b2, const float* __restrict__ x,
                const float* __restrict__ cs, float* __restrict__ out) {
  __shared__ u16 H[64 * 256];        // 32KB
  __shared__ float Kern[4][16 * 64]; // per-wave 4KB slab, XOR swizzled
  const int tid = threadIdx.x;
  const int lane = tid & 63, wid = tid >> 6;
  const int l15 = lane & 15, l4 = lane >> 4;
  const int d0 = blockIdx.y * 64;
  const int colbase = d0 * 4 + wid * 64;
  const int tg = blockIdx.x;

  // load w2 fragments into registers (once per block) — validated indexing
  bf16x8 bw[8][4];
#pragma unroll
  for (int ks = 0; ks < 8; ++ks)
#pragma unroll
    for (int ni = 0; ni < 4; ++ni)
      bw[ks][ni] = *reinterpret_cast<const bf16x8*>(
          w2T + (size_t)(colbase + ni * 16 + l15) * GHN + ks * 32 + l4 * 8);

  float b2v[4];
#pragma unroll
  for (int ni = 0; ni < 4; ++ni) b2v[ni] = b2[colbase + ni * 16 + l15];

  const int chl = lane & 15, rg = lane >> 4;
  const int d = d0 + wid * 16 + chl;
  float* KW = Kern[wid];

  for (int it = 0; it < 4; ++it) {
    const int t0 = (tg * 4 + it) * 64;

    __syncthreads();  // previous tile's H readers done before overwrite
    // stage h tile: LINEAR copy (h is pre-swizzled), 8 x 16B per thread
#pragma unroll
    for (int p = 0; p < 8; ++p) {
      int idx = p * 256 + tid;  // 0..2047 granules of 8 u16
      *reinterpret_cast<bf16x8*>(&H[(size_t)idx * 8]) =
          *reinterpret_cast<const bf16x8*>(h + (size_t)t0 * GHN + (size_t)idx * 8);
    }
    __syncthreads();

    // ---- GEMM: 8 ks x (4 A-frag ds_read + 16 MFMA), B in registers ----
    f32x4 acc[4][4] = {};
#pragma unroll
    for (int ks = 0; ks < 8; ++ks) {
#pragma unroll
      for (int mi = 0; mi < 4; ++mi) {
        int m = mi * 16 + l15;
        int g = ks * 4 + l4;
        bf16x8 af = *reinterpret_cast<const bf16x8*>(&H[m * 256 + ((g ^ (m & 7)) << 3)]);
#pragma unroll
        for (int ni = 0; ni < 4; ++ni)
          acc[mi][ni] = __builtin_amdgcn_mfma_f32_16x16x32_bf16(af, bw[ks][ni], acc[mi][ni], 0, 0, 0);
      }
    }

    // ---- wave-private conv epilogue (no block barriers needed) ----
    int iseq = 0;
    while (OFFS[iseq + 1] <= t0) ++iseq;
    const int seq_start = OFFS[iseq];

#pragma unroll
    for (int mi = 0; mi < 4; ++mi) {
      asm volatile("" ::: "memory");  // order vs previous mi's reads
      // write 16x64 slab, cols XOR-swizzled (conflict-free, bijective)
#pragma unroll
      for (int ni = 0; ni < 4; ++ni)
#pragma unroll
        for (int r = 0; r < 4; ++r) {
          int row = l4 * 4 + r;
          int cw = ni * 16 + l15;
          KW[row * 64 + (cw ^ ((row & 7) << 2))] = acc[mi][ni][r] + b2v[ni];
        }
      asm volatile("" ::: "memory");  // writes before reads (DS in-order/wave)
      // read 4 taps per (token, channel), conv, silu, store
#pragma unroll
      for (int rr = 0; rr < 4; ++rr) {
        int rl = rg * 4 + rr;
        int token = t0 + mi * 16 + rl;
        f32x4 kv = *reinterpret_cast<const f32x4*>(
            &KW[rl * 64 + ((chl * 4) ^ ((rl & 7) << 2))]);
        float s = 0.0f;
#pragma unroll
        for (int kk = 0; kk < 4; ++kk) {
          int src = token + kk - 3;
          float xv = (src >= seq_start)
                         ? x[(size_t)src * DDIM + d]
                         : cs[((size_t)iseq * DDIM + d) * 3 + (src - seq_start + 3)];
          s += xv * kv[kk];
        }
        out[(size_t)token * DDIM + d] = silu_f(s);
      }
    }
  }
}

// ---------------------------------------------------------------------------
// Kernel C: new_conv_state[i][d][m] = x[offs[i+1]-3+m][d]  (validated)
// ---------------------------------------------------------------------------
__global__ __launch_bounds__(256)
void tail_state(const float* __restrict__ x, float* __restrict__ out2) {
  int idx = blockIdx.x * 256 + threadIdx.x;  // 8*2048*3 = 49152 exactly
  int i = idx / (DDIM * 3);
  int rem = idx - i * (DDIM * 3);
  int d = rem / 3, m = rem - d * 3;
  int token = OFFS[i + 1] - 3 + m;
  out2[idx] = x[(size_t)token * DDIM + d];
}

// ---------------------------------------------------------------------------
extern "C" void kernel_launch(void* const* d_in, const int* in_sizes, int n_in,
                              void* d_out, int out_size, void* d_ws, size_t ws_size,
                              hipStream_t stream) {
  (void)in_sizes; (void)n_in; (void)out_size; (void)ws_size;
  const float* x  = (const float*)d_in[0];
  const float* cs = (const float*)d_in[1];
  const float* gi = (const float*)d_in[2];
  const float* w1 = (const float*)d_in[4];
  const float* w2 = (const float*)d_in[5];
  const float* b2 = (const float*)d_in[6];
  float* out = (float*)d_out;

  char* ws = (char*)d_ws;
  u16* w2T = (u16*)ws;                        // [8192][256] bf16 : 4,194,304 B
  u16* w1T = (u16*)(ws + 4194304);            // [256][2048] bf16 : 1,048,576 B
  u16* h   = (u16*)(ws + 4194304 + 1048576);  // [9728][256] bf16 swizzled : 4,980,736 B

  transpose_bf16_k<<<dim3(8192 / 64, 256 / 64), 256, 0, stream>>>(w2, w2T, GHN, DDIM * 4);
  transpose_bf16_k<<<dim3(256 / 64, 2048 / 64), 256, 0, stream>>>(w1, w1T, DDIM, GHN);
  gemm1_silu<<<T_TOT / 32, 256, 0, stream>>>(gi, w1T, h);
  gemm2_conv<<<dim3(T_TOT / 256, DDIM / 64), 256, 0, stream>>>(h, w2T, b2, x, cs, out);
  tail_state<<<(NSEQ * DDIM * 3) / 256, 256, 0, stream>>>(x, out + (size_t)T_TOT * DDIM);
}

// Round 6
// 213.542 us; speedup vs baseline: 1.3203x; 1.3203x over previous
//
#include <hip/hip_runtime.h>
#include <cstdint>
#include <cstddef>

typedef __attribute__((ext_vector_type(8))) short bf16x8;
typedef __attribute__((ext_vector_type(4))) unsigned short u16x4;
typedef __attribute__((ext_vector_type(4))) float f32x4;
typedef unsigned short u16;

#define T_TOT 9728
#define DDIM  2048
#define GHN   256
#define NSEQ  8

__device__ __constant__ int OFFS[NSEQ + 1] = {0, 512, 1536, 3072, 5120, 5760, 6656, 7936, 9728};

__device__ __forceinline__ u16 f2bf(float f) {
  union { float f; unsigned u; } v; v.f = f;
  unsigned r = v.u + 0x7FFFu + ((v.u >> 16) & 1u);
  return (u16)(r >> 16);
}
__device__ __forceinline__ float silu_f(float v) {
  return v / (1.0f + __expf(-v));
}

// ---------------------------------------------------------------------------
// Prep: fp32 [R][C] -> bf16 [C][R]  (transpose + convert), 64x64 tiles
// ---------------------------------------------------------------------------
__global__ __launch_bounds__(256)
void transpose_bf16_k(const float* __restrict__ in, u16* __restrict__ out, int R, int C) {
  __shared__ float tile[64][65];
  const int c0 = blockIdx.x * 64, r0 = blockIdx.y * 64;
  const int tid = threadIdx.x;
  const int lc = tid & 63, lr = tid >> 6;
#pragma unroll
  for (int p = 0; p < 16; ++p) {
    int r = lr + p * 4;
    tile[r][lc] = in[(size_t)(r0 + r) * C + c0 + lc];
  }
  __syncthreads();
#pragma unroll
  for (int p = 0; p < 16; ++p) {
    int c = lr + p * 4;
    out[(size_t)(c0 + c) * R + r0 + lc] = f2bf(tile[lc][c]);
  }
}

// ---------------------------------------------------------------------------
// Kernel A: h = silu(gi @ w1)  (validated; h stored PRE-SWIZZLED:
// element (t,c) at t*256 + ((c>>3)^(t&7))*8 + (c&7))
// ---------------------------------------------------------------------------
__global__ __launch_bounds__(256, 4)
void gemm1_silu(const float* __restrict__ gi, const u16* __restrict__ w1T,
                u16* __restrict__ h) {
  __shared__ u16 A[32][72];
  const int tid = threadIdx.x;
  const int lane = tid & 63, wid = tid >> 6;
  const int l15 = lane & 15, l4 = lane >> 4;
  const int t0 = blockIdx.x * 32;
  const int nb = wid * 64;

  f32x4 acc[2][4] = {};

  for (int k0 = 0; k0 < DDIM; k0 += 64) {
#pragma unroll
    for (int j = 0; j < 2; ++j) {
      int idx = tid + j * 256;
      int m = idx >> 4, f4 = idx & 15;
      f32x4 v = *reinterpret_cast<const f32x4*>(&gi[(size_t)(t0 + m) * DDIM + k0 + f4 * 4]);
      u16x4 b;
      b[0] = f2bf(v[0]); b[1] = f2bf(v[1]); b[2] = f2bf(v[2]); b[3] = f2bf(v[3]);
      *reinterpret_cast<u16x4*>(&A[m][f4 * 4]) = b;
    }
    __syncthreads();
#pragma unroll
    for (int ks = 0; ks < 2; ++ks) {
      bf16x8 af[2], bfr[4];
#pragma unroll
      for (int mi = 0; mi < 2; ++mi)
        af[mi] = *reinterpret_cast<const bf16x8*>(&A[mi * 16 + l15][ks * 32 + 8 * l4]);
#pragma unroll
      for (int ni = 0; ni < 4; ++ni)
        bfr[ni] = *reinterpret_cast<const bf16x8*>(
            &w1T[(size_t)(nb + ni * 16 + l15) * DDIM + k0 + ks * 32 + 8 * l4]);
#pragma unroll
      for (int mi = 0; mi < 2; ++mi)
#pragma unroll
        for (int ni = 0; ni < 4; ++ni)
          acc[mi][ni] = __builtin_amdgcn_mfma_f32_16x16x32_bf16(af[mi], bfr[ni], acc[mi][ni], 0, 0, 0);
    }
    __syncthreads();
  }

#pragma unroll
  for (int mi = 0; mi < 2; ++mi)
#pragma unroll
    for (int ni = 0; ni < 4; ++ni)
#pragma unroll
      for (int r = 0; r < 4; ++r) {
        float v = silu_f(acc[mi][ni][r]);
        int token = t0 + mi * 16 + l4 * 4 + r;
        int c = nb + ni * 16 + l15;
        int pos = ((((c >> 3) ^ (token & 7)) << 3) | (c & 7));
        h[(size_t)token * GHN + pos] = f2bf(v);
      }
}

// ---------------------------------------------------------------------------
// Kernel B: fused kern = h@w2+b2 -> 4-tap conv -> silu -> out.
// grid (38 tg, 64 n-tiles of 128 cols); 256 thr / 4 waves; wave owns 32 cols
// (8 d). bw[8][2]=64 VGPR register-resident; 4 chunks of 64 tokens per block.
// Kern slab transposed [32 cols][17] f32 (stride-17 kills bank conflicts).
// ---------------------------------------------------------------------------
__global__ __launch_bounds__(256, 3)
void gemm2_conv(const u16* __restrict__ h, const u16* __restrict__ w2T,
                const float* __restrict__ b2, const float* __restrict__ x,
                const float* __restrict__ cs, float* __restrict__ out) {
  __shared__ u16 H[64 * 256];          // 32KB
  __shared__ float Kern[4][32 * 17];   // 4 x 2176B per-wave slabs
  const int tid = threadIdx.x;
  const int lane = tid & 63, wid = tid >> 6;
  const int l15 = lane & 15, l4 = lane >> 4;
  const int colwave = blockIdx.y * 128 + wid * 32;   // wave's 32 kern cols
  const int dwave = colwave >> 2;                    // wave's 8 d channels
  const int tg = blockIdx.x;

  // w2 fragments register-resident (loaded once): 64 VGPR
  bf16x8 bw[8][2];
#pragma unroll
  for (int ks = 0; ks < 8; ++ks)
#pragma unroll
    for (int ni = 0; ni < 2; ++ni)
      bw[ks][ni] = *reinterpret_cast<const bf16x8*>(
          w2T + (size_t)(colwave + ni * 16 + l15) * GHN + ks * 32 + l4 * 8);

  float b2v[2];
#pragma unroll
  for (int ni = 0; ni < 2; ++ni) b2v[ni] = b2[colwave + ni * 16 + l15];

  const int dl = lane & 7, rg = lane >> 3;
  const int d = dwave + dl;
  float* KW = Kern[wid];

  for (int it = 0; it < 4; ++it) {
    const int t0 = (tg * 4 + it) * 64;

    __syncthreads();  // previous chunk's H readers done before overwrite
    // stage h tile: LINEAR copy (h pre-swizzled), 8 x 16B per thread
#pragma unroll
    for (int p = 0; p < 8; ++p) {
      int idx = p * 256 + tid;
      *reinterpret_cast<bf16x8*>(&H[(size_t)idx * 8]) =
          *reinterpret_cast<const bf16x8*>(h + (size_t)t0 * GHN + (size_t)idx * 8);
    }
    __syncthreads();

    // ---- GEMM: 8 ks x (4 A-frag ds_read + 8 MFMA), B in registers ----
    f32x4 acc[4][2] = {};
#pragma unroll
    for (int ks = 0; ks < 8; ++ks) {
#pragma unroll
      for (int mi = 0; mi < 4; ++mi) {
        int m = mi * 16 + l15;
        int g = ks * 4 + l4;
        bf16x8 af = *reinterpret_cast<const bf16x8*>(&H[m * 256 + ((g ^ (m & 7)) << 3)]);
#pragma unroll
        for (int ni = 0; ni < 2; ++ni)
          acc[mi][ni] = __builtin_amdgcn_mfma_f32_16x16x32_bf16(af, bw[ks][ni], acc[mi][ni], 0, 0, 0);
      }
    }

    // ---- wave-private conv epilogue ----
    int iseq = 0;
    while (OFFS[iseq + 1] <= t0) ++iseq;
    const int seq_start = OFFS[iseq];

#pragma unroll
    for (int mi = 0; mi < 4; ++mi) {
      asm volatile("" ::: "memory");
      // write 16 tokens x 32 cols slab, transposed, stride 17
#pragma unroll
      for (int ni = 0; ni < 2; ++ni)
#pragma unroll
        for (int r = 0; r < 4; ++r) {
          int row = l4 * 4 + r;          // token within slab
          int cw = ni * 16 + l15;        // col within wave
          KW[cw * 17 + row] = acc[mi][ni][r] + b2v[ni];
        }
      asm volatile("" ::: "memory");
      // 2 outputs per lane: tokens rg*2, rg*2+1 at channel d
#pragma unroll
      for (int rr = 0; rr < 2; ++rr) {
        int rl = rg * 2 + rr;
        int token = t0 + mi * 16 + rl;
        float s = 0.0f;
#pragma unroll
        for (int kk = 0; kk < 4; ++kk) {
          float kv = KW[(4 * dl + kk) * 17 + rl];
          int src = token + kk - 3;
          float xv = (src >= seq_start)
                         ? x[(size_t)src * DDIM + d]
                         : cs[((size_t)iseq * DDIM + d) * 3 + (src - seq_start + 3)];
          s += xv * kv;
        }
        out[(size_t)token * DDIM + d] = silu_f(s);
      }
    }
  }
}

// ---------------------------------------------------------------------------
// Kernel C: new_conv_state[i][d][m] = x[offs[i+1]-3+m][d]
// ---------------------------------------------------------------------------
__global__ __launch_bounds__(256)
void tail_state(const float* __restrict__ x, float* __restrict__ out2) {
  int idx = blockIdx.x * 256 + threadIdx.x;
  int i = idx / (DDIM * 3);
  int rem = idx - i * (DDIM * 3);
  int d = rem / 3, m = rem - d * 3;
  int token = OFFS[i + 1] - 3 + m;
  out2[idx] = x[(size_t)token * DDIM + d];
}

// ---------------------------------------------------------------------------
extern "C" void kernel_launch(void* const* d_in, const int* in_sizes, int n_in,
                              void* d_out, int out_size, void* d_ws, size_t ws_size,
                              hipStream_t stream) {
  (void)in_sizes; (void)n_in; (void)out_size; (void)ws_size;
  const float* x  = (const float*)d_in[0];
  const float* cs = (const float*)d_in[1];
  const float* gi = (const float*)d_in[2];
  const float* w1 = (const float*)d_in[4];
  const float* w2 = (const float*)d_in[5];
  const float* b2 = (const float*)d_in[6];
  float* out = (float*)d_out;

  char* ws = (char*)d_ws;
  u16* w2T = (u16*)ws;                        // [8192][256] bf16 : 4,194,304 B
  u16* w1T = (u16*)(ws + 4194304);            // [256][2048] bf16 : 1,048,576 B
  u16* h   = (u16*)(ws + 4194304 + 1048576);  // [9728][256] bf16 swizzled : 4,980,736 B

  transpose_bf16_k<<<dim3(8192 / 64, 256 / 64), 256, 0, stream>>>(w2, w2T, GHN, DDIM * 4);
  transpose_bf16_k<<<dim3(256 / 64, 2048 / 64), 256, 0, stream>>>(w1, w1T, DDIM, GHN);
  gemm1_silu<<<T_TOT / 32, 256, 0, stream>>>(gi, w1T, h);
  // each block: 4 waves x 32 cols = 128 of the D*K = 8192 kern columns -> 64 y-blocks
  gemm2_conv<<<dim3(T_TOT / 256, (DDIM * 4) / 128), 256, 0, stream>>>(h, w2T, b2, x, cs, out);
  tail_state<<<(NSEQ * DDIM * 3) / 256, 256, 0, stream>>>(x, out + (size_t)T_TOT * DDIM);
}

// Round 7
// 205.987 us; speedup vs baseline: 1.3687x; 1.0367x over previous
//
#include <hip/hip_runtime.h>
#include <cstdint>
#include <cstddef>

typedef __attribute__((ext_vector_type(8))) short bf16x8;
typedef __attribute__((ext_vector_type(4))) unsigned short u16x4;
typedef __attribute__((ext_vector_type(4))) float f32x4;
typedef unsigned short u16;

#define T_TOT 9728
#define DDIM  2048
#define GHN   256
#define NSEQ  8

__device__ __constant__ int OFFS[NSEQ + 1] = {0, 512, 1536, 3072, 5120, 5760, 6656, 7936, 9728};

__device__ __forceinline__ u16 f2bf(float f) {
  union { float f; unsigned u; } v; v.f = f;
  unsigned r = v.u + 0x7FFFu + ((v.u >> 16) & 1u);
  return (u16)(r >> 16);
}
__device__ __forceinline__ float silu_f(float v) {
  return v / (1.0f + __expf(-v));
}

// ---------------------------------------------------------------------------
// Prep: fp32 [R][C] -> bf16 [C][R]  (transpose + convert), 64x64 tiles
// ---------------------------------------------------------------------------
__global__ __launch_bounds__(256)
void transpose_bf16_k(const float* __restrict__ in, u16* __restrict__ out, int R, int C) {
  __shared__ float tile[64][65];
  const int c0 = blockIdx.x * 64, r0 = blockIdx.y * 64;
  const int tid = threadIdx.x;
  const int lc = tid & 63, lr = tid >> 6;
#pragma unroll
  for (int p = 0; p < 16; ++p) {
    int r = lr + p * 4;
    tile[r][lc] = in[(size_t)(r0 + r) * C + c0 + lc];
  }
  __syncthreads();
#pragma unroll
  for (int p = 0; p < 16; ++p) {
    int c = lr + p * 4;
    out[(size_t)(c0 + c) * R + r0 + lc] = f2bf(tile[lc][c]);
  }
}

// ---------------------------------------------------------------------------
// Kernel A: h = silu(gi @ w1)  (validated; h stored PRE-SWIZZLED:
// element (t,c) at t*256 + ((c>>3)^(t&7))*8 + (c&7))
// ---------------------------------------------------------------------------
__global__ __launch_bounds__(256, 4)
void gemm1_silu(const float* __restrict__ gi, const u16* __restrict__ w1T,
                u16* __restrict__ h) {
  __shared__ u16 A[32][72];
  const int tid = threadIdx.x;
  const int lane = tid & 63, wid = tid >> 6;
  const int l15 = lane & 15, l4 = lane >> 4;
  const int t0 = blockIdx.x * 32;
  const int nb = wid * 64;

  f32x4 acc[2][4] = {};

  for (int k0 = 0; k0 < DDIM; k0 += 64) {
#pragma unroll
    for (int j = 0; j < 2; ++j) {
      int idx = tid + j * 256;
      int m = idx >> 4, f4 = idx & 15;
      f32x4 v = *reinterpret_cast<const f32x4*>(&gi[(size_t)(t0 + m) * DDIM + k0 + f4 * 4]);
      u16x4 b;
      b[0] = f2bf(v[0]); b[1] = f2bf(v[1]); b[2] = f2bf(v[2]); b[3] = f2bf(v[3]);
      *reinterpret_cast<u16x4*>(&A[m][f4 * 4]) = b;
    }
    __syncthreads();
#pragma unroll
    for (int ks = 0; ks < 2; ++ks) {
      bf16x8 af[2], bfr[4];
#pragma unroll
      for (int mi = 0; mi < 2; ++mi)
        af[mi] = *reinterpret_cast<const bf16x8*>(&A[mi * 16 + l15][ks * 32 + 8 * l4]);
#pragma unroll
      for (int ni = 0; ni < 4; ++ni)
        bfr[ni] = *reinterpret_cast<const bf16x8*>(
            &w1T[(size_t)(nb + ni * 16 + l15) * DDIM + k0 + ks * 32 + 8 * l4]);
#pragma unroll
      for (int mi = 0; mi < 2; ++mi)
#pragma unroll
        for (int ni = 0; ni < 4; ++ni)
          acc[mi][ni] = __builtin_amdgcn_mfma_f32_16x16x32_bf16(af[mi], bfr[ni], acc[mi][ni], 0, 0, 0);
    }
    __syncthreads();
  }

#pragma unroll
  for (int mi = 0; mi < 2; ++mi)
#pragma unroll
    for (int ni = 0; ni < 4; ++ni)
#pragma unroll
      for (int r = 0; r < 4; ++r) {
        float v = silu_f(acc[mi][ni][r]);
        int token = t0 + mi * 16 + l4 * 4 + r;
        int c = nb + ni * 16 + l15;
        int pos = ((((c >> 3) ^ (token & 7)) << 3) | (c & 7));
        h[(size_t)token * GHN + pos] = f2bf(v);
      }
}

// ---------------------------------------------------------------------------
// Kernel B: fused kern = h@w2+b2 -> 4-tap conv -> silu -> out.
// grid (38 tg, 64 col-tiles of 128); 256 thr / 4 waves; wave owns 32 cols (8 d).
// bw[8][2]=64 VGPR register-resident. 4 chunks of 64 tokens per block.
// T14 async-stage: next chunk h -> regs before GEMM, ds_write after conv.
// Kern slab [16][36] f32: 2-way write banks, 2-way f32x4 read banks (free).
// ---------------------------------------------------------------------------
__global__ __launch_bounds__(256, 3)
void gemm2_conv(const u16* __restrict__ h, const u16* __restrict__ w2T,
                const float* __restrict__ b2, const float* __restrict__ x,
                const float* __restrict__ cs, float* __restrict__ out) {
  __shared__ u16 H[64 * 256];          // 32KB single buffer
  __shared__ float Kern[4][16 * 36];   // 4 x 2304B per-wave slabs, stride 36
  const int tid = threadIdx.x;
  const int lane = tid & 63, wid = tid >> 6;
  const int l15 = lane & 15, l4 = lane >> 4;
  const int colwave = blockIdx.y * 128 + wid * 32;   // wave's 32 kern cols
  const int dwave = colwave >> 2;                    // wave's 8 d channels
  const int tg = blockIdx.x;

  // w2 fragments register-resident (loaded once): 64 VGPR
  bf16x8 bw[8][2];
#pragma unroll
  for (int ks = 0; ks < 8; ++ks)
#pragma unroll
    for (int ni = 0; ni < 2; ++ni)
      bw[ks][ni] = *reinterpret_cast<const bf16x8*>(
          w2T + (size_t)(colwave + ni * 16 + l15) * GHN + ks * 32 + l4 * 8);

  float b2v[2];
#pragma unroll
  for (int ni = 0; ni < 2; ++ni) b2v[ni] = b2[colwave + ni * 16 + l15];

  const int dl = lane & 7, rg = lane >> 3;  // epilogue mapping: d-lane, row-group
  const int d = dwave + dl;
  float* KW = Kern[wid];

  // prologue: chunk 0 -> regs -> LDS
  bf16x8 pf[8];
  {
    const u16* hb = h + (size_t)(tg * 4) * 64 * GHN;
#pragma unroll
    for (int p = 0; p < 8; ++p)
      pf[p] = *reinterpret_cast<const bf16x8*>(hb + (size_t)(p * 256 + tid) * 8);
#pragma unroll
    for (int p = 0; p < 8; ++p)
      *reinterpret_cast<bf16x8*>(&H[(p * 256 + tid) * 8]) = pf[p];
  }
  __syncthreads();

  for (int it = 0; it < 4; ++it) {
    const int t0 = (tg * 4 + it) * 64;

    // T14: issue next chunk's loads now; latency hides under GEMM+conv
    if (it < 3) {
      const u16* hb = h + (size_t)(t0 + 64) * GHN;
#pragma unroll
      for (int p = 0; p < 8; ++p)
        pf[p] = *reinterpret_cast<const bf16x8*>(hb + (size_t)(p * 256 + tid) * 8);
    }

    // ---- GEMM: 8 ks x (4 A-frag ds_read + 8 MFMA), B in registers ----
    f32x4 acc[4][2] = {};
#pragma unroll
    for (int ks = 0; ks < 8; ++ks) {
#pragma unroll
      for (int mi = 0; mi < 4; ++mi) {
        int m = mi * 16 + l15;
        int g = ks * 4 + l4;
        bf16x8 af = *reinterpret_cast<const bf16x8*>(&H[m * 256 + ((g ^ (m & 7)) << 3)]);
#pragma unroll
        for (int ni = 0; ni < 2; ++ni)
          acc[mi][ni] = __builtin_amdgcn_mfma_f32_16x16x32_bf16(af, bw[ks][ni], acc[mi][ni], 0, 0, 0);
      }
    }

    // ---- wave-private conv epilogue ----
    int iseq = 0;
    while (OFFS[iseq + 1] <= t0) ++iseq;
    const int seq_start = OFFS[iseq];

#pragma unroll
    for (int mi = 0; mi < 4; ++mi) {
      asm volatile("" ::: "memory");
      // write 16 tokens x 32 cols slab: row-major, stride 36 (2-way banks)
#pragma unroll
      for (int ni = 0; ni < 2; ++ni)
#pragma unroll
        for (int r = 0; r < 4; ++r) {
          int row = l4 * 4 + r;
          int cw = ni * 16 + l15;
          KW[row * 36 + cw] = acc[mi][ni][r] + b2v[ni];
        }
      asm volatile("" ::: "memory");
      // x sliding window: 5 scalars cover taps for tokens rg*2, rg*2+1
      float xw[5];
#pragma unroll
      for (int j = 0; j < 5; ++j) {
        int src = t0 + mi * 16 + rg * 2 - 3 + j;
        xw[j] = (src >= seq_start)
                    ? x[(size_t)src * DDIM + d]
                    : cs[((size_t)iseq * DDIM + d) * 3 + (src - seq_start + 3)];
      }
#pragma unroll
      for (int rr = 0; rr < 2; ++rr) {
        int rl = rg * 2 + rr;
        int token = t0 + mi * 16 + rl;
        f32x4 kv = *reinterpret_cast<const f32x4*>(&KW[rl * 36 + 4 * dl]);
        float s = xw[rr] * kv[0] + xw[rr + 1] * kv[1] + xw[rr + 2] * kv[2] + xw[rr + 3] * kv[3];
        out[(size_t)token * DDIM + d] = silu_f(s);
      }
    }

    // publish prefetched chunk to LDS for next iteration
    if (it < 3) {
      __syncthreads();  // all H readers of chunk `it` done
#pragma unroll
      for (int p = 0; p < 8; ++p)
        *reinterpret_cast<bf16x8*>(&H[(p * 256 + tid) * 8]) = pf[p];
      __syncthreads();  // chunk it+1 visible to all
    }
  }
}

// ---------------------------------------------------------------------------
// Kernel C: new_conv_state[i][d][m] = x[offs[i+1]-3+m][d]
// ---------------------------------------------------------------------------
__global__ __launch_bounds__(256)
void tail_state(const float* __restrict__ x, float* __restrict__ out2) {
  int idx = blockIdx.x * 256 + threadIdx.x;
  int i = idx / (DDIM * 3);
  int rem = idx - i * (DDIM * 3);
  int d = rem / 3, m = rem - d * 3;
  int token = OFFS[i + 1] - 3 + m;
  out2[idx] = x[(size_t)token * DDIM + d];
}

// ---------------------------------------------------------------------------
extern "C" void kernel_launch(void* const* d_in, const int* in_sizes, int n_in,
                              void* d_out, int out_size, void* d_ws, size_t ws_size,
                              hipStream_t stream) {
  (void)in_sizes; (void)n_in; (void)out_size; (void)ws_size;
  const float* x  = (const float*)d_in[0];
  const float* cs = (const float*)d_in[1];
  const float* gi = (const float*)d_in[2];
  const float* w1 = (const float*)d_in[4];
  const float* w2 = (const float*)d_in[5];
  const float* b2 = (const float*)d_in[6];
  float* out = (float*)d_out;

  char* ws = (char*)d_ws;
  u16* w2T = (u16*)ws;                        // [8192][256] bf16 : 4,194,304 B
  u16* w1T = (u16*)(ws + 4194304);            // [256][2048] bf16 : 1,048,576 B
  u16* h   = (u16*)(ws + 4194304 + 1048576);  // [9728][256] bf16 swizzled : 4,980,736 B

  transpose_bf16_k<<<dim3(8192 / 64, 256 / 64), 256, 0, stream>>>(w2, w2T, GHN, DDIM * 4);
  transpose_bf16_k<<<dim3(256 / 64, 2048 / 64), 256, 0, stream>>>(w1, w1T, DDIM, GHN);
  gemm1_silu<<<T_TOT / 32, 256, 0, stream>>>(gi, w1T, h);
  // each block: 4 waves x 32 cols = 128 of the D*K = 8192 kern columns -> 64 y-blocks
  gemm2_conv<<<dim3(T_TOT / 256, (DDIM * 4) / 128), 256, 0, stream>>>(h, w2T, b2, x, cs, out);
  tail_state<<<(NSEQ * DDIM * 3) / 256, 256, 0, stream>>>(x, out + (size_t)T_TOT * DDIM);
}